// Round 1
// baseline (249.618 us; speedup 1.0000x reference)
//
#include <hip/hip_runtime.h>
#include <hip/hip_bf16.h>

typedef _Float16 f16;
typedef f16 f16x8 __attribute__((ext_vector_type(8)));
typedef f16 f16x4 __attribute__((ext_vector_type(4)));
typedef float f32x4 __attribute__((ext_vector_type(4)));

#define MFMA_F16(a, b, c) __builtin_amdgcn_mfma_f32_16x16x32_f16((a), (b), (c), 0, 0, 0)

// ---------------------------------------------------------------------------
// async global->LDS 16B copy (wave-uniform base + lane*16 semantics; each lane
// passes its own lds ptr = base + lane*16 so the mapping is consistent)
// ---------------------------------------------------------------------------
__device__ __forceinline__ void ld_lds16(const void* g, void* l) {
  __builtin_amdgcn_global_load_lds((const __attribute__((address_space(1))) void*)g,
                                   (__attribute__((address_space(3))) void*)l, 16, 0, 0);
}

// ---------------------------------------------------------------------------
// cast fp32 -> fp16 for hidden (2M) + 4 weight matrices (1M each), float4-wide
// ---------------------------------------------------------------------------
__global__ __launch_bounds__(256) void cast_all(
    const float* __restrict__ hs, const float* __restrict__ wq,
    const float* __restrict__ wk, const float* __restrict__ wv,
    const float* __restrict__ wo, f16* __restrict__ hb,
    f16* __restrict__ wqb, f16* __restrict__ wkb,
    f16* __restrict__ wvb, f16* __restrict__ wob) {
  int idx = blockIdx.x * 256 + threadIdx.x;  // 1,572,864 float4 chunks total
  const float* src;
  f16* dst;
  int j;
  if (idx < 524288) {  // hidden: 2M floats / 4
    src = hs; dst = hb; j = idx;
  } else {
    int t = idx - 524288;
    int w = t >> 18;      // 262144 float4 per weight
    j = t & 262143;
    src = (w == 0) ? wq : (w == 1) ? wk : (w == 2) ? wv : wo;
    dst = (w == 0) ? wqb : (w == 1) ? wkb : (w == 2) ? wvb : wob;
  }
  float4 v = ((const float4*)src)[j];
  f16x4 o;
  o[0] = (f16)v.x; o[1] = (f16)v.y; o[2] = (f16)v.z; o[3] = (f16)v.w;
  ((f16x4*)dst)[j] = o;
}

// ---------------------------------------------------------------------------
// relative-position bias table: btab[h][rel + 2047], rel = kv - q
// bucket boundaries derived as exact integers from the fp32 reference formula
// ---------------------------------------------------------------------------
__global__ __launch_bounds__(256) void build_bias(const float* __restrict__ rb,
                                                  float* __restrict__ btab) {
  int idx = blockIdx.x * 256 + threadIdx.x;  // 65536 = 16 heads * 4096
  int h = idx >> 12;
  int t = idx & 4095;
  int rel = t - 2047;
  int bucket = (rel > 0) ? 16 : 0;
  int a = (rel < 0) ? -rel : rel;
  int lg;
  if (a < 8) {
    lg = a;
  } else {
    int cnt = (a >= 12) + (a >= 16) + (a >= 23) + (a >= 32) + (a >= 46) +
              (a >= 64) + (a >= 91);
    lg = 8 + cnt;  // max 15
  }
  bucket += lg;
  btab[idx] = rb[bucket * 16 + h];  // rel_bias[32][16]
}

// ---------------------------------------------------------------------------
// GEMM mainloop: C[128x128] tile of A[M,K=1024] * B[N,K=1024]^T (both row-major)
// 256 threads = 4 waves (2x2), each wave 64x64 = 4x4 MFMA frags, BK=32
// ---------------------------------------------------------------------------
__device__ __forceinline__ void gemm_mainloop(const f16* __restrict__ A,
                                              const f16* __restrict__ B,
                                              int brow, int bcol,
                                              f16* lA, f16* lB,
                                              f32x4 acc[4][4]) {
  const int tid = threadIdx.x;
  const int lane = tid & 63;
  const int wave = tid >> 6;
  const int wm = wave >> 1, wn = wave & 1;
  const int lo = lane & 15;
  const int hi8 = (lane >> 4) << 3;
  const f16* ga = A + (size_t)(brow + (tid >> 2)) * 1024 + ((tid & 3) << 3);
  const f16* gb = B + (size_t)(bcol + (tid >> 2)) * 1024 + ((tid & 3) << 3);
  f16* la_dst = lA + tid * 8;
  f16* lb_dst = lB + tid * 8;
  for (int k0 = 0; k0 < 1024; k0 += 32) {
    ld_lds16(ga + k0,             la_dst);
    ld_lds16(ga + k0 + 64 * 1024, la_dst + 2048);
    ld_lds16(gb + k0,             lb_dst);
    ld_lds16(gb + k0 + 64 * 1024, lb_dst + 2048);
    __syncthreads();
    f16x8 af[4], bf[4];
#pragma unroll
    for (int i = 0; i < 4; ++i) {
      af[i] = *(const f16x8*)(lA + (wm * 64 + i * 16 + lo) * 32 + hi8);
      bf[i] = *(const f16x8*)(lB + (wn * 64 + i * 16 + lo) * 32 + hi8);
    }
#pragma unroll
    for (int i = 0; i < 4; ++i)
#pragma unroll
      for (int j = 0; j < 4; ++j)
        acc[i][j] = MFMA_F16(af[i], bf[j], acc[i][j]);
    __syncthreads();
  }
}

// QKV projections fused over blockIdx.z (0=Q, 1=K, 2=V-transposed)
__global__ __launch_bounds__(256) void gemm_qkv(
    const f16* __restrict__ A, const f16* __restrict__ Wq,
    const f16* __restrict__ Wk, const f16* __restrict__ Wv,
    f16* __restrict__ Qo, f16* __restrict__ Ko, f16* __restrict__ VTo) {
  __shared__ __align__(16) f16 lA[128 * 32];
  __shared__ __align__(16) f16 lB[128 * 32];
  const int z = blockIdx.z;
  const f16* B = (z == 0) ? Wq : (z == 1) ? Wk : Wv;
  const int brow = blockIdx.x * 128, bcol = blockIdx.y * 128;
  f32x4 acc[4][4];
#pragma unroll
  for (int i = 0; i < 4; ++i)
#pragma unroll
    for (int j = 0; j < 4; ++j) acc[i][j] = f32x4{0.f, 0.f, 0.f, 0.f};
  gemm_mainloop(A, B, brow, bcol, lA, lB, acc);
  const int lane = threadIdx.x & 63, wave = threadIdx.x >> 6;
  const int wm = wave >> 1, wn = wave & 1;
  const int lo = lane & 15, hi = lane >> 4;
  if (z < 2) {
    f16* C = z ? Ko : Qo;
#pragma unroll
    for (int i = 0; i < 4; ++i)
#pragma unroll
      for (int j = 0; j < 4; ++j) {
        int col = bcol + wn * 64 + j * 16 + lo;
        int row0 = brow + wm * 64 + i * 16 + hi * 4;
#pragma unroll
        for (int r = 0; r < 4; ++r)
          C[(size_t)(row0 + r) * 1024 + col] = (f16)acc[i][j][r];
      }
  } else {
    // V transposed: VT[n][s], n = h*64+dv  (rows contiguous in s -> 8B stores)
#pragma unroll
    for (int i = 0; i < 4; ++i)
#pragma unroll
      for (int j = 0; j < 4; ++j) {
        int col = bcol + wn * 64 + j * 16 + lo;    // n
        int row0 = brow + wm * 64 + i * 16 + hi * 4;  // s
        f16x4 v4;
#pragma unroll
        for (int r = 0; r < 4; ++r) v4[r] = (f16)acc[i][j][r];
        *(f16x4*)(VTo + (size_t)col * 2048 + row0) = v4;
      }
  }
}

// output projection: AO[2048,1024] * Wo[1024,1024]^T -> fp32 d_out
__global__ __launch_bounds__(256) void gemm_out(const f16* __restrict__ A,
                                                const f16* __restrict__ W,
                                                float* __restrict__ C) {
  __shared__ __align__(16) f16 lA[128 * 32];
  __shared__ __align__(16) f16 lB[128 * 32];
  const int brow = blockIdx.x * 128, bcol = blockIdx.y * 128;
  f32x4 acc[4][4];
#pragma unroll
  for (int i = 0; i < 4; ++i)
#pragma unroll
    for (int j = 0; j < 4; ++j) acc[i][j] = f32x4{0.f, 0.f, 0.f, 0.f};
  gemm_mainloop(A, W, brow, bcol, lA, lB, acc);
  const int lane = threadIdx.x & 63, wave = threadIdx.x >> 6;
  const int wm = wave >> 1, wn = wave & 1;
  const int lo = lane & 15, hi = lane >> 4;
#pragma unroll
  for (int i = 0; i < 4; ++i)
#pragma unroll
    for (int j = 0; j < 4; ++j) {
      int col = bcol + wn * 64 + j * 16 + lo;
      int row0 = brow + wm * 64 + i * 16 + hi * 4;
#pragma unroll
      for (int r = 0; r < 4; ++r)
        C[(size_t)(row0 + r) * 1024 + col] = acc[i][j][r];
    }
}

// ---------------------------------------------------------------------------
// Flash attention with T5 relative bias.
// Block = (head, 64 q-rows); 4 waves x 16 q-rows. kv tiles of 64.
// Swapped QK^T: S^T[kv][q] = mfma(K_rows, Q^T) -> softmax lane-local per q.
// PV uses k-map g2(l,j) = (j>>2)*16 + (lane>>4)*4 + (j&3) on BOTH operands.
// ---------------------------------------------------------------------------
__global__ __launch_bounds__(256) void attn_kernel(
    const f16* __restrict__ Q, const f16* __restrict__ K,
    const f16* __restrict__ VT, const float* __restrict__ btab,
    f16* __restrict__ AO) {
  const int h = blockIdx.y;
  const int q0 = blockIdx.x * 64;
  const int tid = threadIdx.x;
  const int wave = tid >> 6, lane = tid & 63;
  const int lo = lane & 15, hi = lane >> 4;
  const int myq = q0 + wave * 16 + lo;  // this lane's q column

  // Q fragments (B-operand, cols = q): held in registers for whole kernel
  f16x8 qf[2];
#pragma unroll
  for (int kk = 0; kk < 2; ++kk)
    qf[kk] = *(const f16x8*)(Q + (size_t)myq * 1024 + h * 64 + kk * 32 + hi * 8);

  float m_run = -1e30f, l_run = 0.f;
  f32x4 oacc[4];
#pragma unroll
  for (int d = 0; d < 4; ++d) oacc[d] = f32x4{0.f, 0.f, 0.f, 0.f};

  const float* bt = btab + h * 4096 + 2047 - myq;
  const f16* Kh = K + h * 64;
  const f16* VTh = VT + (size_t)h * 64 * 2048;

  for (int kv0 = 0; kv0 < 2048; kv0 += 64) {
    // ---- scores S^T (4 frags over kv) ----
    f32x4 sacc[4];
#pragma unroll
    for (int m = 0; m < 4; ++m) sacc[m] = f32x4{0.f, 0.f, 0.f, 0.f};
#pragma unroll
    for (int m = 0; m < 4; ++m) {
#pragma unroll
      for (int kk = 0; kk < 2; ++kk) {
        f16x8 kf = *(const f16x8*)(Kh + (size_t)(kv0 + m * 16 + lo) * 1024 +
                                   kk * 32 + hi * 8);
        sacc[m] = MFMA_F16(kf, qf[kk], sacc[m]);
      }
    }
    // ---- bias + online softmax (per lane: fixed q=myq, 16 kv values) ----
    float p[16];
    float mx = -1e30f;
#pragma unroll
    for (int m = 0; m < 4; ++m)
#pragma unroll
      for (int r = 0; r < 4; ++r) {
        int kv = kv0 + m * 16 + hi * 4 + r;
        float s = sacc[m][r] + bt[kv];
        p[m * 4 + r] = s;
        mx = fmaxf(mx, s);
      }
    mx = fmaxf(mx, __shfl_xor(mx, 16, 64));
    mx = fmaxf(mx, __shfl_xor(mx, 32, 64));
    float m_new = fmaxf(m_run, mx);
    float scale = __expf(m_run - m_new);
    float psum = 0.f;
#pragma unroll
    for (int i = 0; i < 16; ++i) {
      p[i] = __expf(p[i] - m_new);
      psum += p[i];
    }
    psum += __shfl_xor(psum, 16, 64);
    psum += __shfl_xor(psum, 32, 64);
    l_run = l_run * scale + psum;
    m_run = m_new;
#pragma unroll
    for (int d = 0; d < 4; ++d) oacc[d] *= scale;
    // ---- P -> f16 fragments (B-operand of PV, k-map g2) ----
    f16x8 pf[2];
#pragma unroll
    for (int kk = 0; kk < 2; ++kk)
#pragma unroll
      for (int j = 0; j < 8; ++j)
        pf[kk][j] = (f16)p[(kk * 2 + (j >> 2)) * 4 + (j & 3)];
    // ---- PV: A-operand = V^T rows with same k-map g2 ----
#pragma unroll
    for (int d = 0; d < 4; ++d) {
#pragma unroll
      for (int kk = 0; kk < 2; ++kk) {
        const f16* vp = VTh + (size_t)(d * 16 + lo) * 2048 + kv0 + kk * 32 + hi * 4;
        f16x4 v_lo = *(const f16x4*)(vp);
        f16x4 v_hi = *(const f16x4*)(vp + 16);
        f16x8 vf;
#pragma unroll
        for (int r = 0; r < 4; ++r) { vf[r] = v_lo[r]; vf[r + 4] = v_hi[r]; }
        oacc[d] = MFMA_F16(vf, pf[kk], oacc[d]);
      }
    }
  }
  // ---- epilogue: O[dv][q] / l -> AO[s][h*64+dv] ----
  float inv = 1.f / l_run;
#pragma unroll
  for (int d = 0; d < 4; ++d) {
    f16x4 ov;
#pragma unroll
    for (int r = 0; r < 4; ++r) ov[r] = (f16)(oacc[d][r] * inv);
    *(f16x4*)(AO + (size_t)myq * 1024 + h * 64 + d * 16 + hi * 4) = ov;
  }
}

// ---------------------------------------------------------------------------
extern "C" void kernel_launch(void* const* d_in, const int* in_sizes, int n_in,
                              void* d_out, int out_size, void* d_ws, size_t ws_size,
                              hipStream_t stream) {
  const float* hs = (const float*)d_in[0];
  const float* wq = (const float*)d_in[1];
  const float* wk = (const float*)d_in[2];
  const float* wv = (const float*)d_in[3];
  const float* wo = (const float*)d_in[4];
  const float* rb = (const float*)d_in[5];

  char* w = (char*)d_ws;
  f16* hb  = (f16*)w; w += (size_t)2048 * 1024 * 2;
  f16* wqb = (f16*)w; w += (size_t)1024 * 1024 * 2;
  f16* wkb = (f16*)w; w += (size_t)1024 * 1024 * 2;
  f16* wvb = (f16*)w; w += (size_t)1024 * 1024 * 2;
  f16* wob = (f16*)w; w += (size_t)1024 * 1024 * 2;
  f16* Qb  = (f16*)w; w += (size_t)2048 * 1024 * 2;
  f16* Kb  = (f16*)w; w += (size_t)2048 * 1024 * 2;
  f16* VTb = (f16*)w; w += (size_t)2048 * 1024 * 2;
  f16* AOb = (f16*)w; w += (size_t)2048 * 1024 * 2;
  float* btab = (float*)w; w += (size_t)16 * 4096 * 4;

  cast_all<<<6144, 256, 0, stream>>>(hs, wq, wk, wv, wo, hb, wqb, wkb, wvb, wob);
  build_bias<<<256, 256, 0, stream>>>(rb, btab);
  gemm_qkv<<<dim3(16, 8, 3), 256, 0, stream>>>(hb, wqb, wkb, wvb, Qb, Kb, VTb);
  attn_kernel<<<dim3(32, 16), 256, 0, stream>>>(Qb, Kb, VTb, btab, AOb);
  gemm_out<<<dim3(16, 8), 256, 0, stream>>>(AOb, wob, (float*)d_out);
}